// Round 5
// baseline (77.036 us; speedup 1.0000x reference)
//
#include <hip/hip_runtime.h>
#include <hip/hip_bf16.h>

// GlobalPoolDistance: RBF-kernel MMD over 3x3 patch unfolds (8,3,64,64) f32.
// N = 62*62 = 3844 patches, d = 27 (padded K=32). SIG2 = 0.2916.
// R5 = R4 + XCD-chunked bijective block swizzle (T1). R4 recap: p-terms baked
// into MFMA pad columns (A scaled by 2L, col27=2L, col28=-L||a||^2; B col27=
// -||b||^2/2, col28=1) so MFMA output IS the exp2 arg; counted-vmcnt
// two-barrier K-loop; split-bf16 3-MFMA gram. Swizzle: 1984 blocks = 8 XCD
// chunks x 248; logical order is locality-sorted (one chunk ~2 images, ~2MB
// working set -> fits 4MiB XCD L2), so gid=(phys&7)*248+(phys>>3) makes
// staging L2-hit instead of L3-latency-bound (R4: FETCH_SIZE=42MB/dispatch).
//
// ws: Ah|Al|Bh|Bl [16][3968][32] bf16 (4 x 4,063,232 B) + acc[32] f32.

#define NP    3844
#define NPAD  3968
#define KP    32

static constexpr float L_F   = 4.9475824173972215f;   // log2(e)/0.2916
static constexpr float C2L_F = 9.895164834794443f;    // 2*L

using bf16x8 = __attribute__((ext_vector_type(8))) short;
using f32x4  = __attribute__((ext_vector_type(4))) float;

__device__ inline unsigned short f2bf(float f) {
    union { float f; unsigned u; } v; v.f = f;
    unsigned r = v.u + 0x7FFFu + ((v.u >> 16) & 1u);   // RNE (no NaN inputs)
    return (unsigned short)(r >> 16);
}
__device__ inline float bf2f(unsigned short h) {
    union { unsigned u; float f; } v; v.u = ((unsigned)h) << 16;
    return v.f;
}
__device__ inline void pack_store(unsigned short* dst, const unsigned short* v) {
    uint4* d = (uint4*)dst;
#pragma unroll
    for (int q = 0; q < 4; ++q) {
        unsigned w0 = (unsigned)v[8 * q + 0] | ((unsigned)v[8 * q + 1] << 16);
        unsigned w1 = (unsigned)v[8 * q + 2] | ((unsigned)v[8 * q + 3] << 16);
        unsigned w2 = (unsigned)v[8 * q + 4] | ((unsigned)v[8 * q + 5] << 16);
        unsigned w3 = (unsigned)v[8 * q + 6] | ((unsigned)v[8 * q + 7] << 16);
        d[q] = make_uint4(w0, w1, w2, w3);
    }
}

// One thread per (im, patch). A-side scaled by 2L with p-cols; B-side plain.
__global__ __launch_bounds__(256) void gp_prep(const float* __restrict__ x,
                                               const float* __restrict__ y,
                                               unsigned short* __restrict__ Ah,
                                               unsigned short* __restrict__ Al,
                                               unsigned short* __restrict__ Bh,
                                               unsigned short* __restrict__ Bl,
                                               float* __restrict__ acc) {
    if (blockIdx.x == 0 && threadIdx.x < 32) acc[threadIdx.x] = 0.0f;
    int i = blockIdx.x * 256 + threadIdx.x;          // 16*NPAD = 63488
    if (i >= 16 * NPAD) return;
    int n = i % NPAD, im = i / NPAD;
    int b = im & 7;
    const float* src = (im >> 3) ? y : x;

    unsigned short hA[32], lA[32], hB[32], lB[32];
#pragma unroll
    for (int k = 0; k < 32; ++k) { hA[k] = 0; lA[k] = 0; hB[k] = 0; lB[k] = 0; }

    float sq = 0.0f;
    const bool valid = (n < NP);
    if (valid) {
        int r = n / 62, c = n % 62;
#pragma unroll
        for (int ch = 0; ch < 3; ++ch)
#pragma unroll
            for (int pr = 0; pr < 3; ++pr)
#pragma unroll
                for (int pc = 0; pc < 3; ++pc) {
                    int k = ch * 9 + pr * 3 + pc;
                    float v = src[(((b * 3 + ch) * 64) + r + pr) * 64 + (c + pc)];
                    unsigned short hb = f2bf(v);
                    hB[k] = hb; lB[k] = f2bf(v - bf2f(hb));
                    float sv = C2L_F * v;
                    unsigned short ha = f2bf(sv);
                    hA[k] = ha; lA[k] = f2bf(sv - bf2f(ha));
                    sq = fmaf(v, v, sq);
                }
    }
    // col 27: A = 2L (const), B = -sq/2 (pad: -1e30 -> exp2 -> 0)
    {
        unsigned short h = f2bf(C2L_F);
        hA[27] = h; lA[27] = f2bf(C2L_F - bf2f(h));
        float tb = valid ? -0.5f * sq : -1e30f;
        unsigned short hb = f2bf(tb);
        hB[27] = hb; lB[27] = f2bf(tb - bf2f(hb));
    }
    // col 28: A = -L*sq (pad: -1e30), B = 1
    {
        float pa = valid ? -L_F * sq : -1e30f;
        unsigned short ha = f2bf(pa);
        hA[28] = ha; lA[28] = f2bf(pa - bf2f(ha));
        hB[28] = f2bf(1.0f); lB[28] = 0;
    }

    pack_store(Ah + (size_t)i * KP, hA);
    pack_store(Al + (size_t)i * KP, lA);
    pack_store(Bh + (size_t)i * KP, hB);
    pack_store(Bl + (size_t)i * KP, lB);
}

// Stage one 128-col B tile (hi+lo, 16KB) transposed to [side][kslot][col*16]:
// linear LDS dest (global_load_lds rule), permuted per-lane global source.
__device__ inline void stage_tile(const unsigned short* __restrict__ Bh,
                                  const unsigned short* __restrict__ Bl,
                                  int imB, int colBase, char* buf, int w, int l) {
#pragma unroll
    for (int j = 0; j < 4; ++j) {
        int q = w * 4 + j;                 // 16 chunks of 1KB
        int side = q >> 3, slot = (q >> 1) & 3, ch = q & 1;
        const unsigned short* src = (side ? Bl : Bh)
            + ((size_t)(imB * NPAD + colBase + ch * 64 + l)) * KP + slot * 8;
        char* dst = buf + side * 8192 + slot * 2048 + ch * 1024;
        __builtin_amdgcn_global_load_lds(
            (const __attribute__((address_space(1))) void*)src,
            (__attribute__((address_space(3))) void*)dst, 16, 0, 0);
    }
}

__device__ inline void item_of(int sym, int xyStrip, int pb, int len1, int idx,
                               int& strip, int& col, float& wt) {
    if (!sym)            { strip = xyStrip;  col = idx;                  wt = 1.0f; }
    else if (idx < len1) { strip = pb;       col = pb + idx;             wt = (idx == 0) ? 1.0f : 2.0f; }
    else                 { strip = 30 - pb;  col = strip + (idx - len1); wt = (idx == len1) ? 1.0f : 2.0f; }
}

// 1984 blocks x <=8 column tiles. 992 xy (b,strip,quarter) + 992 sym
// (type,b,paired-strip,quarter). Two-barrier counted-vmcnt pipeline.
// Physical->logical XCD-chunked swizzle: XCD j (phys%8==j) gets logical
// chunk [j*248,(j+1)*248), whose A/B panels (~2MB) fit its 4MiB L2.
__global__ __launch_bounds__(256) void gp_pairs5(const unsigned short* __restrict__ Ah,
                                                 const unsigned short* __restrict__ Al,
                                                 const unsigned short* __restrict__ Bh,
                                                 const unsigned short* __restrict__ Bl,
                                                 float* __restrict__ acc) {
    __shared__ __align__(16) char lds[2][16384];   // exactly 32KB -> 5 blocks/CU

    const int phys = blockIdx.x;
    const int gid = (phys & 7) * 248 + (phys >> 3);   // bijective, 1984 = 8*248

    int type, b, imA, imB, sym = 0, xyStrip = 0, pb = 0, len1 = 0, i0, i1;
    if (gid < 992) {
        type = 0; b = gid / 124; int r = gid % 124;
        xyStrip = r >> 2; int q = r & 3;
        i0 = q * 8; i1 = (q == 3) ? 31 : i0 + 8;
        imA = b; imB = 8 + b;
    } else {
        sym = 1;
        int id2 = gid - 992; type = 1 + id2 / 496; int r = id2 % 496;
        b = r / 62; int u = r % 62;
        int q;
        if (u >= 60) { pb = 15; q = u - 60; } else { pb = u >> 2; q = u & 3; }
        len1 = 31 - pb;
        i0 = q * 8; i1 = i0 + 8;                 // pb==15: q in {0,1}, total 16
        imA = (type == 1) ? b : 8 + b; imB = imA;
    }

    const int t = threadIdx.x;
    const int w = t >> 6, l = t & 63, l15 = l & 15, lhi = l >> 4;
    const int colw = (w & 1) * 64;

    bf16x8 ah[4], al[4];
    int curStrip = -1;
    float sacc = 0.0f;

    int strip, col; float wt;
    item_of(sym, xyStrip, pb, len1, i0, strip, col, wt);
    stage_tile(Bh, Bl, imB, col * 128, &lds[0][0], w, l);   // i0 is even

    for (int idx = i0; idx < i1; ++idx) {
        const int cur = idx & 1;
        item_of(sym, xyStrip, pb, len1, idx, strip, col, wt);

        // A-frag loads FIRST (older than the prefetch below -> compiler's
        // pre-MFMA wait is vmcnt(4), leaving the prefetch in flight).
        if (strip != curStrip) {
            curStrip = strip;
            int rowBase = strip * 128 + (w >> 1) * 64;
#pragma unroll
            for (int rg = 0; rg < 4; ++rg) {
                size_t e = ((size_t)(imA * NPAD + rowBase + rg * 16 + l15)) * KP + lhi * 8;
                ah[rg] = *(const bf16x8*)(Ah + e);
                al[rg] = *(const bf16x8*)(Al + e);
            }
        }

        if (idx + 1 < i1) {
            int s2, c2; float w2;
            item_of(sym, xyStrip, pb, len1, idx + 1, s2, c2, w2);
            stage_tile(Bh, Bl, imB, c2 * 128, &lds[cur ^ 1][0], w, l);
            // wait current tile's 4 staging loads (oldest), keep prefetch live
            asm volatile("s_waitcnt vmcnt(4)\n\ts_barrier" ::: "memory");
        } else {
            asm volatile("s_waitcnt vmcnt(0)\n\ts_barrier" ::: "memory");
        }

        const char* bb = &lds[cur][0];
        bf16x8 bh[4], bl[4];
#pragma unroll
        for (int cg = 0; cg < 4; ++cg) {
            int off = lhi * 2048 + (colw + cg * 16 + l15) * 16;
            bh[cg] = *(const bf16x8*)(bb + off);
            bl[cg] = *(const bf16x8*)(bb + 8192 + off);
        }

        float s0 = 0.f, s1 = 0.f, s2e = 0.f, s3 = 0.f;
#pragma unroll
        for (int rg = 0; rg < 4; ++rg)
#pragma unroll
            for (int cg = 0; cg < 4; ++cg) {
                f32x4 g = {0.f, 0.f, 0.f, 0.f};
                g = __builtin_amdgcn_mfma_f32_16x16x32_bf16(al[rg], bh[cg], g, 0, 0, 0);
                g = __builtin_amdgcn_mfma_f32_16x16x32_bf16(ah[rg], bl[cg], g, 0, 0, 0);
                g = __builtin_amdgcn_mfma_f32_16x16x32_bf16(ah[rg], bh[cg], g, 0, 0, 0);
                s0  += __builtin_amdgcn_exp2f(g[0]);
                s1  += __builtin_amdgcn_exp2f(g[1]);
                s2e += __builtin_amdgcn_exp2f(g[2]);
                s3  += __builtin_amdgcn_exp2f(g[3]);
            }
        sacc = fmaf(wt, (s0 + s1) + (s2e + s3), sacc);

        // read-protection barrier: own LDS reads landed, no vmcnt drain
        asm volatile("s_waitcnt lgkmcnt(0)\n\ts_barrier" ::: "memory");
    }

    // block reduce (reuse lds; all staging/readers done past last barrier)
#pragma unroll
    for (int o = 32; o > 0; o >>= 1) sacc += __shfl_down(sacc, o, 64);
    float* red = (float*)&lds[0][0];
    if (l == 0) red[w] = sacc;
    __syncthreads();
    if (t == 0) atomicAdd(&acc[type * 8 + b], (red[0] + red[1]) + (red[2] + red[3]));
}

__global__ void gp_final(const float* __restrict__ acc, float* __restrict__ out) {
    if (threadIdx.x == 0) {
        double s = 0.0;
        for (int b = 0; b < 8; ++b)
            s += -2.0 * (double)acc[b] + (double)acc[8 + b] + (double)acc[16 + b];
        out[0] = (float)(s / (8.0 * (double)NP * (double)NP));
    }
}

extern "C" void kernel_launch(void* const* d_in, const int* in_sizes, int n_in,
                              void* d_out, int out_size, void* d_ws, size_t ws_size,
                              hipStream_t stream) {
    const float* x = (const float*)d_in[0];
    const float* y = (const float*)d_in[1];
    const size_t MSZ = (size_t)16 * NPAD * KP;
    unsigned short* Ah = (unsigned short*)d_ws;
    unsigned short* Al = Ah + MSZ;
    unsigned short* Bh = Al + MSZ;
    unsigned short* Bl = Bh + MSZ;
    float* acc = (float*)(Bl + MSZ);

    gp_prep<<<(16 * NPAD) / 256, 256, 0, stream>>>(x, y, Ah, Al, Bh, Bl, acc);
    gp_pairs5<<<1984, 256, 0, stream>>>(Ah, Al, Bh, Bl, acc);
    gp_final<<<1, 1, 0, stream>>>(acc, (float*)d_out);
}

// Round 6
// 72.586 us; speedup vs baseline: 1.0613x; 1.0613x over previous
//
#include <hip/hip_runtime.h>
#include <hip/hip_bf16.h>

// GlobalPoolDistance: RBF-kernel MMD over 3x3 patch unfolds (8,3,64,64) f32.
// N = 62*62 = 3844 patches, d = 27 (padded K=32). SIG2 = 0.2916.
// R6 = R5 + register-pressure fix: __launch_bounds__(256,4) lifts the VGPR
// cap 64->128 (R5 asm: 64 VGPRs = operands only -> sub-tile MFMA chains fully
// serialized, 2424 cyc/CU-tile vs ~600 pipe-sum), and the inner loop runs two
// independent accumulator chains (ga/gb) so MFMA latency overlaps exp2 work.
// R5 recap: p-terms baked into MFMA pad cols (MFMA out IS the exp2 arg),
// split-bf16 3-MFMA gram, counted-vmcnt two-barrier loop, XCD-chunked swizzle.
//
// ws: Ah|Al|Bh|Bl [16][3968][32] bf16 (4 x 4,063,232 B) + acc[32] f32.

#define NP    3844
#define NPAD  3968
#define KP    32

static constexpr float L_F   = 4.9475824173972215f;   // log2(e)/0.2916
static constexpr float C2L_F = 9.895164834794443f;    // 2*L

using bf16x8 = __attribute__((ext_vector_type(8))) short;
using f32x4  = __attribute__((ext_vector_type(4))) float;

__device__ inline unsigned short f2bf(float f) {
    union { float f; unsigned u; } v; v.f = f;
    unsigned r = v.u + 0x7FFFu + ((v.u >> 16) & 1u);   // RNE (no NaN inputs)
    return (unsigned short)(r >> 16);
}
__device__ inline float bf2f(unsigned short h) {
    union { unsigned u; float f; } v; v.u = ((unsigned)h) << 16;
    return v.f;
}
__device__ inline void pack_store(unsigned short* dst, const unsigned short* v) {
    uint4* d = (uint4*)dst;
#pragma unroll
    for (int q = 0; q < 4; ++q) {
        unsigned w0 = (unsigned)v[8 * q + 0] | ((unsigned)v[8 * q + 1] << 16);
        unsigned w1 = (unsigned)v[8 * q + 2] | ((unsigned)v[8 * q + 3] << 16);
        unsigned w2 = (unsigned)v[8 * q + 4] | ((unsigned)v[8 * q + 5] << 16);
        unsigned w3 = (unsigned)v[8 * q + 6] | ((unsigned)v[8 * q + 7] << 16);
        d[q] = make_uint4(w0, w1, w2, w3);
    }
}

// One thread per (im, patch). A-side scaled by 2L with p-cols; B-side plain.
__global__ __launch_bounds__(256) void gp_prep(const float* __restrict__ x,
                                               const float* __restrict__ y,
                                               unsigned short* __restrict__ Ah,
                                               unsigned short* __restrict__ Al,
                                               unsigned short* __restrict__ Bh,
                                               unsigned short* __restrict__ Bl,
                                               float* __restrict__ acc) {
    if (blockIdx.x == 0 && threadIdx.x < 32) acc[threadIdx.x] = 0.0f;
    int i = blockIdx.x * 256 + threadIdx.x;          // 16*NPAD = 63488
    if (i >= 16 * NPAD) return;
    int n = i % NPAD, im = i / NPAD;
    int b = im & 7;
    const float* src = (im >> 3) ? y : x;

    unsigned short hA[32], lA[32], hB[32], lB[32];
#pragma unroll
    for (int k = 0; k < 32; ++k) { hA[k] = 0; lA[k] = 0; hB[k] = 0; lB[k] = 0; }

    float sq = 0.0f;
    const bool valid = (n < NP);
    if (valid) {
        int r = n / 62, c = n % 62;
#pragma unroll
        for (int ch = 0; ch < 3; ++ch)
#pragma unroll
            for (int pr = 0; pr < 3; ++pr)
#pragma unroll
                for (int pc = 0; pc < 3; ++pc) {
                    int k = ch * 9 + pr * 3 + pc;
                    float v = src[(((b * 3 + ch) * 64) + r + pr) * 64 + (c + pc)];
                    unsigned short hb = f2bf(v);
                    hB[k] = hb; lB[k] = f2bf(v - bf2f(hb));
                    float sv = C2L_F * v;
                    unsigned short ha = f2bf(sv);
                    hA[k] = ha; lA[k] = f2bf(sv - bf2f(ha));
                    sq = fmaf(v, v, sq);
                }
    }
    // col 27: A = 2L (const), B = -sq/2 (pad: -1e30 -> exp2 -> 0)
    {
        unsigned short h = f2bf(C2L_F);
        hA[27] = h; lA[27] = f2bf(C2L_F - bf2f(h));
        float tb = valid ? -0.5f * sq : -1e30f;
        unsigned short hb = f2bf(tb);
        hB[27] = hb; lB[27] = f2bf(tb - bf2f(hb));
    }
    // col 28: A = -L*sq (pad: -1e30), B = 1
    {
        float pa = valid ? -L_F * sq : -1e30f;
        unsigned short ha = f2bf(pa);
        hA[28] = ha; lA[28] = f2bf(pa - bf2f(ha));
        hB[28] = f2bf(1.0f); lB[28] = 0;
    }

    pack_store(Ah + (size_t)i * KP, hA);
    pack_store(Al + (size_t)i * KP, lA);
    pack_store(Bh + (size_t)i * KP, hB);
    pack_store(Bl + (size_t)i * KP, lB);
}

// Stage one 128-col B tile (hi+lo, 16KB) transposed to [side][kslot][col*16]:
// linear LDS dest (global_load_lds rule), permuted per-lane global source.
__device__ inline void stage_tile(const unsigned short* __restrict__ Bh,
                                  const unsigned short* __restrict__ Bl,
                                  int imB, int colBase, char* buf, int w, int l) {
#pragma unroll
    for (int j = 0; j < 4; ++j) {
        int q = w * 4 + j;                 // 16 chunks of 1KB
        int side = q >> 3, slot = (q >> 1) & 3, ch = q & 1;
        const unsigned short* src = (side ? Bl : Bh)
            + ((size_t)(imB * NPAD + colBase + ch * 64 + l)) * KP + slot * 8;
        char* dst = buf + side * 8192 + slot * 2048 + ch * 1024;
        __builtin_amdgcn_global_load_lds(
            (const __attribute__((address_space(1))) void*)src,
            (__attribute__((address_space(3))) void*)dst, 16, 0, 0);
    }
}

__device__ inline void item_of(int sym, int xyStrip, int pb, int len1, int idx,
                               int& strip, int& col, float& wt) {
    if (!sym)            { strip = xyStrip;  col = idx;                  wt = 1.0f; }
    else if (idx < len1) { strip = pb;       col = pb + idx;             wt = (idx == 0) ? 1.0f : 2.0f; }
    else                 { strip = 30 - pb;  col = strip + (idx - len1); wt = (idx == len1) ? 1.0f : 2.0f; }
}

// 1984 blocks x <=8 column tiles. 992 xy (b,strip,quarter) + 992 sym
// (type,b,paired-strip,quarter). Two-barrier counted-vmcnt pipeline.
// XCD-chunked swizzle: XCD j gets logical chunk [j*248,(j+1)*248) (~2MB
// panels -> fits 4MiB XCD L2).
__global__ __launch_bounds__(256, 4) void gp_pairs6(const unsigned short* __restrict__ Ah,
                                                    const unsigned short* __restrict__ Al,
                                                    const unsigned short* __restrict__ Bh,
                                                    const unsigned short* __restrict__ Bl,
                                                    float* __restrict__ acc) {
    __shared__ __align__(16) char lds[2][16384];   // 32KB

    const int phys = blockIdx.x;
    const int gid = (phys & 7) * 248 + (phys >> 3);   // bijective, 1984 = 8*248

    int type, b, imA, imB, sym = 0, xyStrip = 0, pb = 0, len1 = 0, i0, i1;
    if (gid < 992) {
        type = 0; b = gid / 124; int r = gid % 124;
        xyStrip = r >> 2; int q = r & 3;
        i0 = q * 8; i1 = (q == 3) ? 31 : i0 + 8;
        imA = b; imB = 8 + b;
    } else {
        sym = 1;
        int id2 = gid - 992; type = 1 + id2 / 496; int r = id2 % 496;
        b = r / 62; int u = r % 62;
        int q;
        if (u >= 60) { pb = 15; q = u - 60; } else { pb = u >> 2; q = u & 3; }
        len1 = 31 - pb;
        i0 = q * 8; i1 = i0 + 8;                 // pb==15: q in {0,1}, total 16
        imA = (type == 1) ? b : 8 + b; imB = imA;
    }

    const int t = threadIdx.x;
    const int w = t >> 6, l = t & 63, l15 = l & 15, lhi = l >> 4;
    const int colw = (w & 1) * 64;

    bf16x8 ah[4], al[4];
    int curStrip = -1;
    float sacc = 0.0f;

    int strip, col; float wt;
    item_of(sym, xyStrip, pb, len1, i0, strip, col, wt);
    stage_tile(Bh, Bl, imB, col * 128, &lds[0][0], w, l);   // i0 is even

    for (int idx = i0; idx < i1; ++idx) {
        const int cur = idx & 1;
        item_of(sym, xyStrip, pb, len1, idx, strip, col, wt);

        // A-frag loads FIRST (older than the prefetch below -> compiler's
        // pre-MFMA wait is vmcnt(4), leaving the prefetch in flight).
        if (strip != curStrip) {
            curStrip = strip;
            int rowBase = strip * 128 + (w >> 1) * 64;
#pragma unroll
            for (int rg = 0; rg < 4; ++rg) {
                size_t e = ((size_t)(imA * NPAD + rowBase + rg * 16 + l15)) * KP + lhi * 8;
                ah[rg] = *(const bf16x8*)(Ah + e);
                al[rg] = *(const bf16x8*)(Al + e);
            }
        }

        if (idx + 1 < i1) {
            int s2, c2; float w2;
            item_of(sym, xyStrip, pb, len1, idx + 1, s2, c2, w2);
            stage_tile(Bh, Bl, imB, c2 * 128, &lds[cur ^ 1][0], w, l);
            // wait current tile's 4 staging loads (oldest), keep prefetch live
            asm volatile("s_waitcnt vmcnt(4)\n\ts_barrier" ::: "memory");
        } else {
            asm volatile("s_waitcnt vmcnt(0)\n\ts_barrier" ::: "memory");
        }

        const char* bb = &lds[cur][0];
        bf16x8 bh[4], bl[4];
#pragma unroll
        for (int cg = 0; cg < 4; ++cg) {
            int off = lhi * 2048 + (colw + cg * 16 + l15) * 16;
            bh[cg] = *(const bf16x8*)(bb + off);
            bl[cg] = *(const bf16x8*)(bb + 8192 + off);
        }

        float s0 = 0.f, s1 = 0.f, s2e = 0.f, s3 = 0.f;
#pragma unroll
        for (int rg = 0; rg < 4; ++rg)
#pragma unroll
            for (int cgp = 0; cgp < 2; ++cgp) {
                // two independent accumulator chains in flight (ga, gb):
                // MFMA latency of one overlaps issue/trans of the other.
                const int c0 = cgp * 2, c1 = c0 + 1;
                f32x4 ga = {0.f, 0.f, 0.f, 0.f};
                f32x4 gb = {0.f, 0.f, 0.f, 0.f};
                ga = __builtin_amdgcn_mfma_f32_16x16x32_bf16(al[rg], bh[c0], ga, 0, 0, 0);
                gb = __builtin_amdgcn_mfma_f32_16x16x32_bf16(al[rg], bh[c1], gb, 0, 0, 0);
                ga = __builtin_amdgcn_mfma_f32_16x16x32_bf16(ah[rg], bl[c0], ga, 0, 0, 0);
                gb = __builtin_amdgcn_mfma_f32_16x16x32_bf16(ah[rg], bl[c1], gb, 0, 0, 0);
                ga = __builtin_amdgcn_mfma_f32_16x16x32_bf16(ah[rg], bh[c0], ga, 0, 0, 0);
                gb = __builtin_amdgcn_mfma_f32_16x16x32_bf16(ah[rg], bh[c1], gb, 0, 0, 0);
                s0  += __builtin_amdgcn_exp2f(ga[0]);
                s1  += __builtin_amdgcn_exp2f(ga[1]);
                s2e += __builtin_amdgcn_exp2f(ga[2]);
                s3  += __builtin_amdgcn_exp2f(ga[3]);
                s0  += __builtin_amdgcn_exp2f(gb[0]);
                s1  += __builtin_amdgcn_exp2f(gb[1]);
                s2e += __builtin_amdgcn_exp2f(gb[2]);
                s3  += __builtin_amdgcn_exp2f(gb[3]);
            }
        sacc = fmaf(wt, (s0 + s1) + (s2e + s3), sacc);

        // read-protection barrier: own LDS reads landed, no vmcnt drain
        asm volatile("s_waitcnt lgkmcnt(0)\n\ts_barrier" ::: "memory");
    }

    // block reduce (reuse lds; all staging/readers done past last barrier)
#pragma unroll
    for (int o = 32; o > 0; o >>= 1) sacc += __shfl_down(sacc, o, 64);
    float* red = (float*)&lds[0][0];
    if (l == 0) red[w] = sacc;
    __syncthreads();
    if (t == 0) atomicAdd(&acc[type * 8 + b], (red[0] + red[1]) + (red[2] + red[3]));
}

__global__ void gp_final(const float* __restrict__ acc, float* __restrict__ out) {
    if (threadIdx.x == 0) {
        double s = 0.0;
        for (int b = 0; b < 8; ++b)
            s += -2.0 * (double)acc[b] + (double)acc[8 + b] + (double)acc[16 + b];
        out[0] = (float)(s / (8.0 * (double)NP * (double)NP));
    }
}

extern "C" void kernel_launch(void* const* d_in, const int* in_sizes, int n_in,
                              void* d_out, int out_size, void* d_ws, size_t ws_size,
                              hipStream_t stream) {
    const float* x = (const float*)d_in[0];
    const float* y = (const float*)d_in[1];
    const size_t MSZ = (size_t)16 * NPAD * KP;
    unsigned short* Ah = (unsigned short*)d_ws;
    unsigned short* Al = Ah + MSZ;
    unsigned short* Bh = Al + MSZ;
    unsigned short* Bl = Bh + MSZ;
    float* acc = (float*)(Bl + MSZ);

    gp_prep<<<(16 * NPAD) / 256, 256, 0, stream>>>(x, y, Ah, Al, Bh, Bl, acc);
    gp_pairs6<<<1984, 256, 0, stream>>>(Ah, Al, Bh, Bl, acc);
    gp_final<<<1, 1, 0, stream>>>(acc, (float*)d_out);
}

// Round 7
// 72.533 us; speedup vs baseline: 1.0621x; 1.0007x over previous
//
#include <hip/hip_runtime.h>
#include <hip/hip_bf16.h>

// GlobalPoolDistance: RBF-kernel MMD over 3x3 patch unfolds (8,3,64,64) f32.
// N = 62*62 = 3844 patches, d = 27 (padded K=32). SIG2 = 0.2916.
// R7 = R6 with the inner loop restructured for chain ILP: per cg, FOUR
// independent rg-chains share one B fragment (B read per-cg from LDS), exp2s
// batched after the chains. R6 evidence: VGPR stayed 64 -> allocator was
// serializing chains to reuse registers (9000 cyc/block-iter vs ~800 pipe
// sum). Live set now ~100 VGPR < 128 cap from __launch_bounds__(256,4).
// Recap: p-terms baked into MFMA pad cols (MFMA out IS the exp2 arg),
// split-bf16 3-MFMA gram, counted-vmcnt two-barrier loop, XCD-chunked
// swizzle (FETCH 42->12MB in R5).
//
// ws: Ah|Al|Bh|Bl [16][3968][32] bf16 (4 x 4,063,232 B) + acc[32] f32.

#define NP    3844
#define NPAD  3968
#define KP    32

static constexpr float L_F   = 4.9475824173972215f;   // log2(e)/0.2916
static constexpr float C2L_F = 9.895164834794443f;    // 2*L

using bf16x8 = __attribute__((ext_vector_type(8))) short;
using f32x4  = __attribute__((ext_vector_type(4))) float;

#define MFMA16(a, b, c) __builtin_amdgcn_mfma_f32_16x16x32_bf16((a), (b), (c), 0, 0, 0)

__device__ inline unsigned short f2bf(float f) {
    union { float f; unsigned u; } v; v.f = f;
    unsigned r = v.u + 0x7FFFu + ((v.u >> 16) & 1u);   // RNE (no NaN inputs)
    return (unsigned short)(r >> 16);
}
__device__ inline float bf2f(unsigned short h) {
    union { unsigned u; float f; } v; v.u = ((unsigned)h) << 16;
    return v.f;
}
__device__ inline void pack_store(unsigned short* dst, const unsigned short* v) {
    uint4* d = (uint4*)dst;
#pragma unroll
    for (int q = 0; q < 4; ++q) {
        unsigned w0 = (unsigned)v[8 * q + 0] | ((unsigned)v[8 * q + 1] << 16);
        unsigned w1 = (unsigned)v[8 * q + 2] | ((unsigned)v[8 * q + 3] << 16);
        unsigned w2 = (unsigned)v[8 * q + 4] | ((unsigned)v[8 * q + 5] << 16);
        unsigned w3 = (unsigned)v[8 * q + 6] | ((unsigned)v[8 * q + 7] << 16);
        d[q] = make_uint4(w0, w1, w2, w3);
    }
}

// One thread per (im, patch). A-side scaled by 2L with p-cols; B-side plain.
__global__ __launch_bounds__(256) void gp_prep(const float* __restrict__ x,
                                               const float* __restrict__ y,
                                               unsigned short* __restrict__ Ah,
                                               unsigned short* __restrict__ Al,
                                               unsigned short* __restrict__ Bh,
                                               unsigned short* __restrict__ Bl,
                                               float* __restrict__ acc) {
    if (blockIdx.x == 0 && threadIdx.x < 32) acc[threadIdx.x] = 0.0f;
    int i = blockIdx.x * 256 + threadIdx.x;          // 16*NPAD = 63488
    if (i >= 16 * NPAD) return;
    int n = i % NPAD, im = i / NPAD;
    int b = im & 7;
    const float* src = (im >> 3) ? y : x;

    unsigned short hA[32], lA[32], hB[32], lB[32];
#pragma unroll
    for (int k = 0; k < 32; ++k) { hA[k] = 0; lA[k] = 0; hB[k] = 0; lB[k] = 0; }

    float sq = 0.0f;
    const bool valid = (n < NP);
    if (valid) {
        int r = n / 62, c = n % 62;
#pragma unroll
        for (int ch = 0; ch < 3; ++ch)
#pragma unroll
            for (int pr = 0; pr < 3; ++pr)
#pragma unroll
                for (int pc = 0; pc < 3; ++pc) {
                    int k = ch * 9 + pr * 3 + pc;
                    float v = src[(((b * 3 + ch) * 64) + r + pr) * 64 + (c + pc)];
                    unsigned short hb = f2bf(v);
                    hB[k] = hb; lB[k] = f2bf(v - bf2f(hb));
                    float sv = C2L_F * v;
                    unsigned short ha = f2bf(sv);
                    hA[k] = ha; lA[k] = f2bf(sv - bf2f(ha));
                    sq = fmaf(v, v, sq);
                }
    }
    // col 27: A = 2L (const), B = -sq/2 (pad: -1e30 -> exp2 -> 0)
    {
        unsigned short h = f2bf(C2L_F);
        hA[27] = h; lA[27] = f2bf(C2L_F - bf2f(h));
        float tb = valid ? -0.5f * sq : -1e30f;
        unsigned short hb = f2bf(tb);
        hB[27] = hb; lB[27] = f2bf(tb - bf2f(hb));
    }
    // col 28: A = -L*sq (pad: -1e30), B = 1
    {
        float pa = valid ? -L_F * sq : -1e30f;
        unsigned short ha = f2bf(pa);
        hA[28] = ha; lA[28] = f2bf(pa - bf2f(ha));
        hB[28] = f2bf(1.0f); lB[28] = 0;
    }

    pack_store(Ah + (size_t)i * KP, hA);
    pack_store(Al + (size_t)i * KP, lA);
    pack_store(Bh + (size_t)i * KP, hB);
    pack_store(Bl + (size_t)i * KP, lB);
}

// Stage one 128-col B tile (hi+lo, 16KB) transposed to [side][kslot][col*16]:
// linear LDS dest (global_load_lds rule), permuted per-lane global source.
__device__ inline void stage_tile(const unsigned short* __restrict__ Bh,
                                  const unsigned short* __restrict__ Bl,
                                  int imB, int colBase, char* buf, int w, int l) {
#pragma unroll
    for (int j = 0; j < 4; ++j) {
        int q = w * 4 + j;                 // 16 chunks of 1KB
        int side = q >> 3, slot = (q >> 1) & 3, ch = q & 1;
        const unsigned short* src = (side ? Bl : Bh)
            + ((size_t)(imB * NPAD + colBase + ch * 64 + l)) * KP + slot * 8;
        char* dst = buf + side * 8192 + slot * 2048 + ch * 1024;
        __builtin_amdgcn_global_load_lds(
            (const __attribute__((address_space(1))) void*)src,
            (__attribute__((address_space(3))) void*)dst, 16, 0, 0);
    }
}

__device__ inline void item_of(int sym, int xyStrip, int pb, int len1, int idx,
                               int& strip, int& col, float& wt) {
    if (!sym)            { strip = xyStrip;  col = idx;                  wt = 1.0f; }
    else if (idx < len1) { strip = pb;       col = pb + idx;             wt = (idx == 0) ? 1.0f : 2.0f; }
    else                 { strip = 30 - pb;  col = strip + (idx - len1); wt = (idx == len1) ? 1.0f : 2.0f; }
}

// 1984 blocks x <=8 column tiles. 992 xy (b,strip,quarter) + 992 sym
// (type,b,paired-strip,quarter). Two-barrier counted-vmcnt pipeline.
// XCD-chunked swizzle: XCD j gets logical chunk [j*248,(j+1)*248).
__global__ __launch_bounds__(256, 4) void gp_pairs7(const unsigned short* __restrict__ Ah,
                                                    const unsigned short* __restrict__ Al,
                                                    const unsigned short* __restrict__ Bh,
                                                    const unsigned short* __restrict__ Bl,
                                                    float* __restrict__ acc) {
    __shared__ __align__(16) char lds[2][16384];   // 32KB

    const int phys = blockIdx.x;
    const int gid = (phys & 7) * 248 + (phys >> 3);   // bijective, 1984 = 8*248

    int type, b, imA, imB, sym = 0, xyStrip = 0, pb = 0, len1 = 0, i0, i1;
    if (gid < 992) {
        type = 0; b = gid / 124; int r = gid % 124;
        xyStrip = r >> 2; int q = r & 3;
        i0 = q * 8; i1 = (q == 3) ? 31 : i0 + 8;
        imA = b; imB = 8 + b;
    } else {
        sym = 1;
        int id2 = gid - 992; type = 1 + id2 / 496; int r = id2 % 496;
        b = r / 62; int u = r % 62;
        int q;
        if (u >= 60) { pb = 15; q = u - 60; } else { pb = u >> 2; q = u & 3; }
        len1 = 31 - pb;
        i0 = q * 8; i1 = i0 + 8;                 // pb==15: q in {0,1}, total 16
        imA = (type == 1) ? b : 8 + b; imB = imA;
    }

    const int t = threadIdx.x;
    const int w = t >> 6, l = t & 63, l15 = l & 15, lhi = l >> 4;
    const int colw = (w & 1) * 64;

    bf16x8 ah[4], al[4];
    int curStrip = -1;
    float sacc = 0.0f;

    int strip, col; float wt;
    item_of(sym, xyStrip, pb, len1, i0, strip, col, wt);
    stage_tile(Bh, Bl, imB, col * 128, &lds[0][0], w, l);   // i0 is even

    for (int idx = i0; idx < i1; ++idx) {
        const int cur = idx & 1;
        item_of(sym, xyStrip, pb, len1, idx, strip, col, wt);

        // A-frag loads FIRST (older than the prefetch below -> compiler's
        // pre-MFMA wait is vmcnt(4), leaving the prefetch in flight).
        if (strip != curStrip) {
            curStrip = strip;
            int rowBase = strip * 128 + (w >> 1) * 64;
#pragma unroll
            for (int rg = 0; rg < 4; ++rg) {
                size_t e = ((size_t)(imA * NPAD + rowBase + rg * 16 + l15)) * KP + lhi * 8;
                ah[rg] = *(const bf16x8*)(Ah + e);
                al[rg] = *(const bf16x8*)(Al + e);
            }
        }

        if (idx + 1 < i1) {
            int s2, c2; float w2;
            item_of(sym, xyStrip, pb, len1, idx + 1, s2, c2, w2);
            stage_tile(Bh, Bl, imB, c2 * 128, &lds[cur ^ 1][0], w, l);
            // wait current tile's 4 staging loads (oldest), keep prefetch live
            asm volatile("s_waitcnt vmcnt(4)\n\ts_barrier" ::: "memory");
        } else {
            asm volatile("s_waitcnt vmcnt(0)\n\ts_barrier" ::: "memory");
        }

        const char* bb = &lds[cur][0];
        float s0 = 0.f, s1 = 0.f, s2e = 0.f, s3 = 0.f;

#pragma unroll
        for (int cg = 0; cg < 4; ++cg) {
            // B fragment for this column group (short live range)
            const int off = lhi * 2048 + (colw + cg * 16 + l15) * 16;
            const bf16x8 bhc = *(const bf16x8*)(bb + off);
            const bf16x8 blc = *(const bf16x8*)(bb + 8192 + off);
            // FOUR independent rg-chains in flight, sharing bhc/blc:
            // dependent-issue spacing 4 x 4.85cyc ~ MFMA latency.
            f32x4 g0 = {0.f, 0.f, 0.f, 0.f};
            f32x4 g1 = {0.f, 0.f, 0.f, 0.f};
            f32x4 g2 = {0.f, 0.f, 0.f, 0.f};
            f32x4 g3 = {0.f, 0.f, 0.f, 0.f};
            g0 = MFMA16(al[0], bhc, g0);
            g1 = MFMA16(al[1], bhc, g1);
            g2 = MFMA16(al[2], bhc, g2);
            g3 = MFMA16(al[3], bhc, g3);
            g0 = MFMA16(ah[0], blc, g0);
            g1 = MFMA16(ah[1], blc, g1);
            g2 = MFMA16(ah[2], blc, g2);
            g3 = MFMA16(ah[3], blc, g3);
            g0 = MFMA16(ah[0], bhc, g0);
            g1 = MFMA16(ah[1], bhc, g1);
            g2 = MFMA16(ah[2], bhc, g2);
            g3 = MFMA16(ah[3], bhc, g3);
            // exp2 batch (overlaps next cg's MFMAs in the unrolled body)
            s0  += __builtin_amdgcn_exp2f(g0[0]);
            s1  += __builtin_amdgcn_exp2f(g0[1]);
            s2e += __builtin_amdgcn_exp2f(g0[2]);
            s3  += __builtin_amdgcn_exp2f(g0[3]);
            s0  += __builtin_amdgcn_exp2f(g1[0]);
            s1  += __builtin_amdgcn_exp2f(g1[1]);
            s2e += __builtin_amdgcn_exp2f(g1[2]);
            s3  += __builtin_amdgcn_exp2f(g1[3]);
            s0  += __builtin_amdgcn_exp2f(g2[0]);
            s1  += __builtin_amdgcn_exp2f(g2[1]);
            s2e += __builtin_amdgcn_exp2f(g2[2]);
            s3  += __builtin_amdgcn_exp2f(g2[3]);
            s0  += __builtin_amdgcn_exp2f(g3[0]);
            s1  += __builtin_amdgcn_exp2f(g3[1]);
            s2e += __builtin_amdgcn_exp2f(g3[2]);
            s3  += __builtin_amdgcn_exp2f(g3[3]);
        }
        sacc = fmaf(wt, (s0 + s1) + (s2e + s3), sacc);

        // read-protection barrier: own LDS reads landed, no vmcnt drain
        asm volatile("s_waitcnt lgkmcnt(0)\n\ts_barrier" ::: "memory");
    }

    // block reduce (reuse lds; all staging/readers done past last barrier)
#pragma unroll
    for (int o = 32; o > 0; o >>= 1) sacc += __shfl_down(sacc, o, 64);
    float* red = (float*)&lds[0][0];
    if (l == 0) red[w] = sacc;
    __syncthreads();
    if (t == 0) atomicAdd(&acc[type * 8 + b], (red[0] + red[1]) + (red[2] + red[3]));
}

__global__ void gp_final(const float* __restrict__ acc, float* __restrict__ out) {
    if (threadIdx.x == 0) {
        double s = 0.0;
        for (int b = 0; b < 8; ++b)
            s += -2.0 * (double)acc[b] + (double)acc[8 + b] + (double)acc[16 + b];
        out[0] = (float)(s / (8.0 * (double)NP * (double)NP));
    }
}

extern "C" void kernel_launch(void* const* d_in, const int* in_sizes, int n_in,
                              void* d_out, int out_size, void* d_ws, size_t ws_size,
                              hipStream_t stream) {
    const float* x = (const float*)d_in[0];
    const float* y = (const float*)d_in[1];
    const size_t MSZ = (size_t)16 * NPAD * KP;
    unsigned short* Ah = (unsigned short*)d_ws;
    unsigned short* Al = Ah + MSZ;
    unsigned short* Bh = Al + MSZ;
    unsigned short* Bl = Bh + MSZ;
    float* acc = (float*)(Bl + MSZ);

    gp_prep<<<(16 * NPAD) / 256, 256, 0, stream>>>(x, y, Ah, Al, Bh, Bl, acc);
    gp_pairs7<<<1984, 256, 0, stream>>>(Ah, Al, Bh, Bl, acc);
    gp_final<<<1, 1, 0, stream>>>(acc, (float*)d_out);
}